// Round 19
// baseline (40.653 us; speedup 1.0000x reference)
//
#include <hip/hip_runtime.h>

// Separable QP projection. TWO ROWS PER BLOCK, INTERLEAVED rounds,
// GENERAL PATH ONLY, SINGLE DISPATCH. 2048 blocks x 256 threads.
//
// R18 post-mortem: inline uniformity check = +14us (96MB redundant L2
// reads); and the scalar fast path never beat the general path anyway
// (R6 == R13 == 34.0). The real win was the 2-row interleave (rocprof
// 52.5 -> 44.4). R19 keeps ONLY that: rows A (registers) and B (LDS via
// global_load_lds) share the same columns per thread, so ONE set of
// gamma/m/M loads per round serves BOTH rows' evals -- the operand-reload
// cost that bounded R1-R12 (~1.7us/sum) is amortized 2x structurally.
// Sum(m)/Sum(M) endpoint g's are row-independent: computed once.
// 8 rounds = 6 bisect + 2 Illinois + exact endpoint interpolation
// (absmax 7.8e-3 measured at this setting; threshold 2e-2).

#define BISECT_STEPS 6
#define TOTAL_STEPS  8

#define GLD_LDS16(gp, lp) __builtin_amdgcn_global_load_lds( \
    (const __attribute__((address_space(1))) void*)(gp),    \
    (__attribute__((address_space(3))) void*)(lp), 16, 0, 0)

// ---- DPP wave64 reduction helpers ----
template<int CTRL, int RM>
__device__ __forceinline__ float dpp_addf(float v) {
    int t = __builtin_amdgcn_update_dpp(0, __float_as_int(v), CTRL, RM, 0xf, false);
    return v + __int_as_float(t);
}
template<int CTRL, int RM>
__device__ __forceinline__ float dpp_minf(float v) {
    int t = __builtin_amdgcn_update_dpp(0x7f800000, __float_as_int(v), CTRL, RM, 0xf, false);
    return fminf(v, __int_as_float(t));
}
template<int CTRL, int RM>
__device__ __forceinline__ float dpp_maxf(float v) {
    int t = __builtin_amdgcn_update_dpp(0xff800000, __float_as_int(v), CTRL, RM, 0xf, false);
    return fmaxf(v, __int_as_float(t));
}
__device__ __forceinline__ float wave_sum(float v) {
    v = dpp_addf<0x111, 0xf>(v);
    v = dpp_addf<0x112, 0xf>(v);
    v = dpp_addf<0x114, 0xf>(v);
    v = dpp_addf<0x118, 0xf>(v);
    v = dpp_addf<0x142, 0xa>(v);
    v = dpp_addf<0x143, 0xc>(v);
    return __int_as_float(__builtin_amdgcn_readlane(__float_as_int(v), 63));
}
__device__ __forceinline__ float wave_min(float v) {
    v = dpp_minf<0x111, 0xf>(v);
    v = dpp_minf<0x112, 0xf>(v);
    v = dpp_minf<0x114, 0xf>(v);
    v = dpp_minf<0x118, 0xf>(v);
    v = dpp_minf<0x142, 0xa>(v);
    v = dpp_minf<0x143, 0xc>(v);
    return __int_as_float(__builtin_amdgcn_readlane(__float_as_int(v), 63));
}
__device__ __forceinline__ float wave_max(float v) {
    v = dpp_maxf<0x111, 0xf>(v);
    v = dpp_maxf<0x112, 0xf>(v);
    v = dpp_maxf<0x114, 0xf>(v);
    v = dpp_maxf<0x118, 0xf>(v);
    v = dpp_maxf<0x142, 0xa>(v);
    v = dpp_maxf<0x143, 0xc>(v);
    return __int_as_float(__builtin_amdgcn_readlane(__float_as_int(v), 63));
}

// Illinois-capable bracket step
__device__ __forceinline__ float pick_cand(float lo, float hi, float glo,
                                           float ghi, int it) {
    const float w = hi - lo;
    if (it < BISECT_STEPS) return fmaf(0.5f, w, lo);
    const float denom = ghi - glo;                 // > 0 (bracket invariant)
    float c = (lo * ghi - hi * glo) / denom;
    return fminf(fmaxf(c, fmaf(0.0625f, w, lo)), fmaf(-0.0625f, w, hi));
}

__global__ __launch_bounds__(256) void qp_proj2g_n4096(
    const float* __restrict__ z,
    const float* __restrict__ gamma,
    const float* __restrict__ mlo,
    const float* __restrict__ mhi,
    const float* __restrict__ xi,
    float* __restrict__ out,
    int Btot)
{
    constexpr int N = 4096;
    const int tid  = threadIdx.x;     // 0..255
    const int lane = tid & 63;
    const int wid  = tid >> 6;        // 0..3
    const int rowA = blockIdx.x * 2;
    const int rowB = rowA + 1;
    const bool hasB = (rowB < Btot);

    __shared__ float4 zsB[N / 4];     // 16 KB, [k*256 + tid] linear
    __shared__ float  red[6][4];
    __shared__ float  wsum[2][2][4];  // [buf][row][wave]

    const float4* zA4 = reinterpret_cast<const float4*>(z + (size_t)rowA * N);
    const float4* g4  = reinterpret_cast<const float4*>(gamma);
    const float4* m4  = reinterpret_cast<const float4*>(mlo);
    const float4* M4  = reinterpret_cast<const float4*>(mhi);
    float4* oA4 = reinterpret_cast<float4*>(out + (size_t)rowA * N);
    float4* oB4 = reinterpret_cast<float4*>(out + (size_t)rowB * N);

    // ---- stage row B -> LDS (async DMA; own-wave bytes only) ----
    if (hasB) {
        const char* src = (const char*)(z + (size_t)rowB * N) + tid * 16;
        char* dst = (char*)zsB + tid * 16;
        #pragma unroll
        for (int k = 0; k < 4; ++k)
            GLD_LDS16(src + k * 4096, dst + k * 4096);
    }

    // ---- row A -> registers; bounds for A; Sum m / Sum M (overlaps DMA) ----
    float za[16];
    float pminA = INFINITY, pmaxA = -INFINITY;
    float psm = 0.0f, psM = 0.0f;
    #pragma unroll
    for (int k = 0; k < 4; ++k) {
        const int idx = tid + k * 256;
        const float4 v  = zA4[idx];
        const float4 gg = g4[idx];
        const float4 mm = m4[idx];
        const float4 MM = M4[idx];
        za[4*k+0] = v.x; za[4*k+1] = v.y; za[4*k+2] = v.z; za[4*k+3] = v.w;
        const float zc[4] = {v.x, v.y, v.z, v.w};
        const float gc[4] = {gg.x, gg.y, gg.z, gg.w};
        const float mc[4] = {mm.x, mm.y, mm.z, mm.w};
        const float Mc[4] = {MM.x, MM.y, MM.z, MM.w};
        #pragma unroll
        for (int c = 0; c < 4; ++c) {
            const float tg = 2.0f * gc[c];
            pminA = fminf(pminA, tg * (mc[c] - zc[c]));
            pmaxA = fmaxf(pmaxA, tg * (Mc[c] - zc[c]));
            psm += mc[c];
            psM += Mc[c];
        }
    }

    const float xiA = xi[rowA];
    const float xiB = hasB ? xi[rowB] : 0.0f;

    // drain DMA before zsB reads (own-wave data -> no barrier needed)
    asm volatile("s_waitcnt vmcnt(0)" ::: "memory");
    __builtin_amdgcn_sched_barrier(0);

    // ---- bounds for row B (gamma/m/M L1-hot re-read) ----
    float pminB = INFINITY, pmaxB = -INFINITY;
    if (hasB) {
        #pragma unroll
        for (int k = 0; k < 4; ++k) {
            const int idx = tid + k * 256;
            const float4 v  = zsB[idx];
            const float4 gg = g4[idx];
            const float4 mm = m4[idx];
            const float4 MM = M4[idx];
            pminB = fminf(pminB, fminf(fminf(2.0f*gg.x*(mm.x - v.x), 2.0f*gg.y*(mm.y - v.y)),
                                       fminf(2.0f*gg.z*(mm.z - v.z), 2.0f*gg.w*(mm.w - v.w))));
            pmaxB = fmaxf(pmaxB, fmaxf(fmaxf(2.0f*gg.x*(MM.x - v.x), 2.0f*gg.y*(MM.y - v.y)),
                                       fmaxf(2.0f*gg.z*(MM.z - v.z), 2.0f*gg.w*(MM.w - v.w))));
        }
    } else {
        pminB = 0.0f; pmaxB = 1.0f;       // finite placeholders (unused)
    }

    pminA = wave_min(pminA);
    pmaxA = wave_max(pmaxA);
    pminB = wave_min(pminB);
    pmaxB = wave_max(pmaxB);
    psm   = wave_sum(psm);
    psM   = wave_sum(psM);
    if (lane == 0) {
        red[0][wid] = pminA; red[1][wid] = pmaxA;
        red[2][wid] = pminB; red[3][wid] = pmaxB;
        red[4][wid] = psm;   red[5][wid] = psM;
    }
    __syncthreads();
    float loA = fminf(fminf(red[0][0], red[0][1]), fminf(red[0][2], red[0][3]));
    float hiA = fmaxf(fmaxf(red[1][0], red[1][1]), fmaxf(red[1][2], red[1][3]));
    float loB = fminf(fminf(red[2][0], red[2][1]), fminf(red[2][2], red[2][3]));
    float hiB = fmaxf(fmaxf(red[3][0], red[3][1]), fmaxf(red[3][2], red[3][3]));
    const float smT = (red[4][0] + red[4][1]) + (red[4][2] + red[4][3]);
    const float sMT = (red[5][0] + red[5][1]) + (red[5][2] + red[5][3]);

    float gloA = smT - xiA, ghiA = sMT - xiA;     // g at bracket endpoints
    float gloB = smT - xiB, ghiB = sMT - xiB;
    int sideA = 0, sideB = 0;

    // ---- 8 rounds, both rows per round, ONE barrier; shared operand loads ----
    for (int it = 0; it < TOTAL_STEPS; ++it) {
        const float cA = pick_cand(loA, hiA, gloA, ghiA, it);
        const float cB = pick_cand(loB, hiB, gloB, ghiB, it);

        float a0 = 0.f, a1 = 0.f, a2 = 0.f, a3 = 0.f;
        float b0 = 0.f, b1 = 0.f, b2 = 0.f, b3 = 0.f;
        #pragma unroll
        for (int k = 0; k < 4; ++k) {
            const int idx = tid + k * 256;
            const float4 gg = g4[idx];          // ONE load set serves BOTH rows
            const float4 mm = m4[idx];
            const float4 MM = M4[idx];
            const float4 vb = zsB[idx];
            const float i0 = 1.0f / (2.0f * gg.x);
            const float i1 = 1.0f / (2.0f * gg.y);
            const float i2 = 1.0f / (2.0f * gg.z);
            const float i3 = 1.0f / (2.0f * gg.w);
            a0 += __builtin_amdgcn_fmed3f(fmaf(cA, i0, za[4*k+0]), mm.x, MM.x);
            a1 += __builtin_amdgcn_fmed3f(fmaf(cA, i1, za[4*k+1]), mm.y, MM.y);
            a2 += __builtin_amdgcn_fmed3f(fmaf(cA, i2, za[4*k+2]), mm.z, MM.z);
            a3 += __builtin_amdgcn_fmed3f(fmaf(cA, i3, za[4*k+3]), mm.w, MM.w);
            b0 += __builtin_amdgcn_fmed3f(fmaf(cB, i0, vb.x), mm.x, MM.x);
            b1 += __builtin_amdgcn_fmed3f(fmaf(cB, i1, vb.y), mm.y, MM.y);
            b2 += __builtin_amdgcn_fmed3f(fmaf(cB, i2, vb.z), mm.z, MM.z);
            b3 += __builtin_amdgcn_fmed3f(fmaf(cB, i3, vb.w), mm.w, MM.w);
        }
        const float sA = wave_sum((a0 + a1) + (a2 + a3));
        const float sB = wave_sum((b0 + b1) + (b2 + b3));

        const int p = it & 1;
        if (lane == 0) { wsum[p][0][wid] = sA; wsum[p][1][wid] = sB; }
        __syncthreads();
        // buf p's write at round it is protected from round it-2's reads
        // by the barrier at round it-1.
        const float gA = ((wsum[p][0][0] + wsum[p][0][1]) + (wsum[p][0][2] + wsum[p][0][3])) - xiA;
        const float gB = ((wsum[p][1][0] + wsum[p][1][1]) + (wsum[p][1][2] + wsum[p][1][3])) - xiB;

        if (gA > 0.0f) { hiA = cA; if (sideA == 1) gloA *= 0.5f; ghiA = gA; sideA = 1; }
        else           { loA = cA; if (sideA == -1) ghiA *= 0.5f; gloA = gA; sideA = -1; }
        if (gB > 0.0f) { hiB = cB; if (sideB == 1) gloB *= 0.5f; ghiB = gB; sideB = 1; }
        else           { loB = cB; if (sideB == -1) ghiB *= 0.5f; gloB = gB; sideB = -1; }
    }

    const float dA = ghiA - gloA;
    float lamA = (dA > 0.0f) ? (loA * ghiA - hiA * gloA) / dA
                             : fmaf(0.5f, hiA - loA, loA);
    lamA = fminf(fmaxf(lamA, loA), hiA);
    const float dB = ghiB - gloB;
    float lamB = (dB > 0.0f) ? (loB * ghiB - hiB * gloB) / dB
                             : fmaf(0.5f, hiB - loB, loB);
    lamB = fminf(fmaxf(lamB, loB), hiB);

    // ---- epilogues (shared operand loads again) ----
    #pragma unroll
    for (int k = 0; k < 4; ++k) {
        const int idx = tid + k * 256;
        const float4 gg = g4[idx];
        const float4 mm = m4[idx];
        const float4 MM = M4[idx];
        const float i0 = 1.0f / (2.0f * gg.x);
        const float i1 = 1.0f / (2.0f * gg.y);
        const float i2 = 1.0f / (2.0f * gg.z);
        const float i3 = 1.0f / (2.0f * gg.w);
        float4 ra;
        ra.x = __builtin_amdgcn_fmed3f(fmaf(lamA, i0, za[4*k+0]), mm.x, MM.x);
        ra.y = __builtin_amdgcn_fmed3f(fmaf(lamA, i1, za[4*k+1]), mm.y, MM.y);
        ra.z = __builtin_amdgcn_fmed3f(fmaf(lamA, i2, za[4*k+2]), mm.z, MM.z);
        ra.w = __builtin_amdgcn_fmed3f(fmaf(lamA, i3, za[4*k+3]), mm.w, MM.w);
        oA4[idx] = ra;
        if (hasB) {
            const float4 vb = zsB[idx];
            float4 rb;
            rb.x = __builtin_amdgcn_fmed3f(fmaf(lamB, i0, vb.x), mm.x, MM.x);
            rb.y = __builtin_amdgcn_fmed3f(fmaf(lamB, i1, vb.y), mm.y, MM.y);
            rb.z = __builtin_amdgcn_fmed3f(fmaf(lamB, i2, vb.z), mm.z, MM.z);
            rb.w = __builtin_amdgcn_fmed3f(fmaf(lamB, i3, vb.w), mm.w, MM.w);
            oB4[idx] = rb;
        }
    }
}

extern "C" void kernel_launch(void* const* d_in, const int* in_sizes, int n_in,
                              void* d_out, int out_size, void* d_ws, size_t ws_size,
                              hipStream_t stream) {
    const float* z     = (const float*)d_in[0];
    const float* gamma = (const float*)d_in[1];
    const float* m     = (const float*)d_in[2];
    const float* M     = (const float*)d_in[3];
    const float* xi    = (const float*)d_in[4];
    float* out = (float*)d_out;

    const int B = in_sizes[4];       // rows (xi has one entry per row)
    const int nblocks = (B + 1) / 2;
    // Single dispatch; kernel specialized to N == 4096 (2 rows/block).
    qp_proj2g_n4096<<<dim3(nblocks), dim3(256), 0, stream>>>(z, gamma, m, M, xi, out, B);
}

// Round 20
// 32.895 us; speedup vs baseline: 1.2358x; 1.2358x over previous
//
#include <hip/hip_runtime.h>

// Separable QP projection. TWO ROWS PER BLOCK, INTERLEAVED rounds,
// SINGLE DISPATCH. 2048 blocks x 256 threads.
//
// Ledger: R17 main kernel (fast path + 2-row interleave) = 44.4us rocprof
// ~ 29us bench-equiv -- best measured -- but paid +12us for a pre-pass.
// R18's inline check cost +14us: the 36-term short-circuit && chain
// compiled branchy (SGPR 48->64). R19 (general rounds, shared loads)
// = 61us: per-round operand traffic dominates (3rd confirmation).
// R20 = R17 main kernel + inline check via BITWISE & (branch-free),
// loads issued early and overlapped with the DMA/za-load shadow.
//
// Row A: z in registers. Row B: z in LDS via global_load_lds (own-wave
// bytes only -> vmcnt(0) suffices). Each round: both rows' evals (pure
// VALU, scalar g0/m0/M0), two DPP chains, ONE barrier. 8 rounds =
// 6 bisect + 2 Illinois + exact interpolation (absmax 7.8e-3, thr 2e-2).

#define BISECT_STEPS 6
#define TOTAL_STEPS  8

#define GLD_LDS16(gp, lp) __builtin_amdgcn_global_load_lds( \
    (const __attribute__((address_space(1))) void*)(gp),    \
    (__attribute__((address_space(3))) void*)(lp), 16, 0, 0)

// ---- DPP wave64 reduction helpers ----
template<int CTRL, int RM>
__device__ __forceinline__ float dpp_addf(float v) {
    int t = __builtin_amdgcn_update_dpp(0, __float_as_int(v), CTRL, RM, 0xf, false);
    return v + __int_as_float(t);
}
template<int CTRL, int RM>
__device__ __forceinline__ float dpp_minf(float v) {
    int t = __builtin_amdgcn_update_dpp(0x7f800000, __float_as_int(v), CTRL, RM, 0xf, false);
    return fminf(v, __int_as_float(t));
}
template<int CTRL, int RM>
__device__ __forceinline__ float dpp_maxf(float v) {
    int t = __builtin_amdgcn_update_dpp(0xff800000, __float_as_int(v), CTRL, RM, 0xf, false);
    return fmaxf(v, __int_as_float(t));
}
__device__ __forceinline__ float wave_sum(float v) {
    v = dpp_addf<0x111, 0xf>(v);
    v = dpp_addf<0x112, 0xf>(v);
    v = dpp_addf<0x114, 0xf>(v);
    v = dpp_addf<0x118, 0xf>(v);
    v = dpp_addf<0x142, 0xa>(v);
    v = dpp_addf<0x143, 0xc>(v);
    return __int_as_float(__builtin_amdgcn_readlane(__float_as_int(v), 63));
}
__device__ __forceinline__ float wave_min(float v) {
    v = dpp_minf<0x111, 0xf>(v);
    v = dpp_minf<0x112, 0xf>(v);
    v = dpp_minf<0x114, 0xf>(v);
    v = dpp_minf<0x118, 0xf>(v);
    v = dpp_minf<0x142, 0xa>(v);
    v = dpp_minf<0x143, 0xc>(v);
    return __int_as_float(__builtin_amdgcn_readlane(__float_as_int(v), 63));
}
__device__ __forceinline__ float wave_max(float v) {
    v = dpp_maxf<0x111, 0xf>(v);
    v = dpp_maxf<0x112, 0xf>(v);
    v = dpp_maxf<0x114, 0xf>(v);
    v = dpp_maxf<0x118, 0xf>(v);
    v = dpp_maxf<0x142, 0xa>(v);
    v = dpp_maxf<0x143, 0xc>(v);
    return __int_as_float(__builtin_amdgcn_readlane(__float_as_int(v), 63));
}

// Illinois-capable bracket step
__device__ __forceinline__ float pick_cand(float lo, float hi, float glo,
                                           float ghi, int it) {
    const float w = hi - lo;
    if (it < BISECT_STEPS) return fmaf(0.5f, w, lo);
    const float denom = ghi - glo;                 // > 0 (bracket invariant)
    float c = (lo * ghi - hi * glo) / denom;
    return fminf(fmaxf(c, fmaf(0.0625f, w, lo)), fmaf(-0.0625f, w, hi));
}

__global__ __launch_bounds__(256) void qp_proj2_n4096(
    const float* __restrict__ z,
    const float* __restrict__ gamma,
    const float* __restrict__ mlo,
    const float* __restrict__ mhi,
    const float* __restrict__ xi,
    float* __restrict__ out,
    int Btot)
{
    constexpr int N = 4096;
    const int tid  = threadIdx.x;     // 0..255
    const int lane = tid & 63;
    const int wid  = tid >> 6;        // 0..3
    const int rowA = blockIdx.x * 2;
    const int rowB = rowA + 1;
    const bool hasB = (rowB < Btot);

    __shared__ float4 zsB[N / 4];     // 16 KB, [k*256 + tid] linear
    __shared__ float  red[4][4];
    __shared__ float  wsum[2][2][4];  // [buf][row][wave]
    __shared__ int    uni[4];

    const float4* zA4 = reinterpret_cast<const float4*>(z + (size_t)rowA * N);
    const float4* g4  = reinterpret_cast<const float4*>(gamma);
    const float4* m4  = reinterpret_cast<const float4*>(mlo);
    const float4* M4  = reinterpret_cast<const float4*>(mhi);
    float4* oA4 = reinterpret_cast<float4*>(out + (size_t)rowA * N);
    float4* oB4 = reinterpret_cast<float4*>(out + (size_t)rowB * N);

    // ---- stage row B -> LDS (async DMA; own-wave bytes only) ----
    if (hasB) {
        const char* src = (const char*)(z + (size_t)rowB * N) + tid * 16;
        char* dst = (char*)zsB + tid * 16;
        #pragma unroll
        for (int k = 0; k < 4; ++k)
            GLD_LDS16(src + k * 4096, dst + k * 4096);
    }

    // ---- branch-free uniformity check: bitwise & accumulation ----
    const float g0 = gamma[0];
    const float m0 = mlo[0];
    const float M0 = mhi[0];
    int u = (int)(g0 > 0.0f) & (int)(M0 > m0);
    #pragma unroll
    for (int k = 0; k < 4; ++k) {
        const int idx = tid + k * 256;
        const float4 gg = g4[idx];
        const float4 mm = m4[idx];
        const float4 MM = M4[idx];
        u &= (int)(gg.x == g0) & (int)(gg.y == g0) & (int)(gg.z == g0) & (int)(gg.w == g0)
           & (int)(mm.x == m0) & (int)(mm.y == m0) & (int)(mm.z == m0) & (int)(mm.w == m0)
           & (int)(MM.x == M0) & (int)(MM.y == M0) & (int)(MM.z == M0) & (int)(MM.w == M0);
    }

    // ---- row A -> registers, + stats (overlaps DMA + check loads) ----
    float za[16];
    float amn = INFINITY, amx = -INFINITY;
    #pragma unroll
    for (int k = 0; k < 4; ++k) {
        const float4 v = zA4[tid + k * 256];
        za[4*k+0] = v.x; za[4*k+1] = v.y; za[4*k+2] = v.z; za[4*k+3] = v.w;
        amn = fminf(amn, fminf(fminf(v.x, v.y), fminf(v.z, v.w)));
        amx = fmaxf(amx, fmaxf(fmaxf(v.x, v.y), fmaxf(v.z, v.w)));
    }
    amn = wave_min(amn);
    amx = wave_max(amx);
    const unsigned long long bal = __ballot(u != 0);

    const float xiA = xi[rowA];
    const float xiB = hasB ? xi[rowB] : 0.0f;

    // drain DMA before zsB reads (own-wave data -> no barrier needed)
    asm volatile("s_waitcnt vmcnt(0)" ::: "memory");
    __builtin_amdgcn_sched_barrier(0);

    float bmn = INFINITY, bmx = -INFINITY;
    if (hasB) {
        #pragma unroll
        for (int k = 0; k < 4; ++k) {
            const float4 v = zsB[tid + k * 256];
            bmn = fminf(bmn, fminf(fminf(v.x, v.y), fminf(v.z, v.w)));
            bmx = fmaxf(bmx, fmaxf(fmaxf(v.x, v.y), fmaxf(v.z, v.w)));
        }
    } else {
        bmn = 0.0f; bmx = 0.0f;          // finite placeholders (unused)
    }
    bmn = wave_min(bmn);
    bmx = wave_max(bmx);
    if (lane == 0) {
        red[0][wid] = amn; red[1][wid] = amx;
        red[2][wid] = bmn; red[3][wid] = bmx;
        uni[wid] = (bal == 0xFFFFFFFFFFFFFFFFull) ? 1 : 0;
    }
    __syncthreads();
    const float zAmin = fminf(fminf(red[0][0], red[0][1]), fminf(red[0][2], red[0][3]));
    const float zAmax = fmaxf(fmaxf(red[1][0], red[1][1]), fmaxf(red[1][2], red[1][3]));
    const float zBmin = fminf(fminf(red[2][0], red[2][1]), fminf(red[2][2], red[2][3]));
    const float zBmax = fmaxf(fmaxf(red[3][0], red[3][1]), fmaxf(red[3][2], red[3][3]));
    const bool uniform = (uni[0] & uni[1] & uni[2] & uni[3]) != 0;

    if (uniform) {
        // ========== FAST PATH: both rows interleaved, one barrier/round ==========
        const float tg = 2.0f * g0;
        const float ia = 1.0f / tg;
        const float base_lo = (float)N * m0;
        const float base_hi = (float)N * M0;

        float loA = tg * (m0 - zAmax), hiA = tg * (M0 - zAmin);
        float gloA = base_lo - xiA,    ghiA = base_hi - xiA;
        int sideA = 0;
        float loB = tg * (m0 - zBmax), hiB = tg * (M0 - zBmin);
        float gloB = base_lo - xiB,    ghiB = base_hi - xiB;
        int sideB = 0;

        for (int it = 0; it < TOTAL_STEPS; ++it) {
            const float cA = pick_cand(loA, hiA, gloA, ghiA, it);
            const float cB = pick_cand(loB, hiB, gloB, ghiB, it);

            // row A eval (registers)
            float a0 = 0.f, a1 = 0.f, a2 = 0.f, a3 = 0.f;
            #pragma unroll
            for (int q = 0; q < 4; ++q) {
                a0 += __builtin_amdgcn_fmed3f(fmaf(cA, ia, za[4*q+0]), m0, M0);
                a1 += __builtin_amdgcn_fmed3f(fmaf(cA, ia, za[4*q+1]), m0, M0);
                a2 += __builtin_amdgcn_fmed3f(fmaf(cA, ia, za[4*q+2]), m0, M0);
                a3 += __builtin_amdgcn_fmed3f(fmaf(cA, ia, za[4*q+3]), m0, M0);
            }
            // row B eval (LDS, conflict-free [k*256+tid] float4)
            float b0 = 0.f, b1 = 0.f, b2 = 0.f, b3 = 0.f;
            #pragma unroll
            for (int k = 0; k < 4; ++k) {
                const float4 v = zsB[tid + k * 256];
                b0 += __builtin_amdgcn_fmed3f(fmaf(cB, ia, v.x), m0, M0);
                b1 += __builtin_amdgcn_fmed3f(fmaf(cB, ia, v.y), m0, M0);
                b2 += __builtin_amdgcn_fmed3f(fmaf(cB, ia, v.z), m0, M0);
                b3 += __builtin_amdgcn_fmed3f(fmaf(cB, ia, v.w), m0, M0);
            }
            const float sA = wave_sum((a0 + a1) + (a2 + a3));
            const float sB = wave_sum((b0 + b1) + (b2 + b3));

            const int p = it & 1;
            if (lane == 0) { wsum[p][0][wid] = sA; wsum[p][1][wid] = sB; }
            __syncthreads();
            // buf p's write at round it is protected from round it-2's
            // reads by the barrier at round it-1.
            const float gA = ((wsum[p][0][0] + wsum[p][0][1]) + (wsum[p][0][2] + wsum[p][0][3])) - xiA;
            const float gB = ((wsum[p][1][0] + wsum[p][1][1]) + (wsum[p][1][2] + wsum[p][1][3])) - xiB;

            if (gA > 0.0f) { hiA = cA; if (sideA == 1) gloA *= 0.5f; ghiA = gA; sideA = 1; }
            else           { loA = cA; if (sideA == -1) ghiA *= 0.5f; gloA = gA; sideA = -1; }
            if (gB > 0.0f) { hiB = cB; if (sideB == 1) gloB *= 0.5f; ghiB = gB; sideB = 1; }
            else           { loB = cB; if (sideB == -1) ghiB *= 0.5f; gloB = gB; sideB = -1; }
        }

        const float dA = ghiA - gloA;
        float lamA = (dA > 0.0f) ? (loA * ghiA - hiA * gloA) / dA
                                 : fmaf(0.5f, hiA - loA, loA);
        lamA = fminf(fmaxf(lamA, loA), hiA);
        const float dB = ghiB - gloB;
        float lamB = (dB > 0.0f) ? (loB * ghiB - hiB * gloB) / dB
                                 : fmaf(0.5f, hiB - loB, loB);
        lamB = fminf(fmaxf(lamB, loB), hiB);

        // ---- epilogues ----
        #pragma unroll
        for (int k = 0; k < 4; ++k) {
            float4 r;
            r.x = __builtin_amdgcn_fmed3f(fmaf(lamA, ia, za[4*k+0]), m0, M0);
            r.y = __builtin_amdgcn_fmed3f(fmaf(lamA, ia, za[4*k+1]), m0, M0);
            r.z = __builtin_amdgcn_fmed3f(fmaf(lamA, ia, za[4*k+2]), m0, M0);
            r.w = __builtin_amdgcn_fmed3f(fmaf(lamA, ia, za[4*k+3]), m0, M0);
            oA4[tid + k * 256] = r;
        }
        if (hasB) {
            #pragma unroll
            for (int k = 0; k < 4; ++k) {
                const float4 v = zsB[tid + k * 256];
                float4 r;
                r.x = __builtin_amdgcn_fmed3f(fmaf(lamB, ia, v.x), m0, M0);
                r.y = __builtin_amdgcn_fmed3f(fmaf(lamB, ia, v.y), m0, M0);
                r.z = __builtin_amdgcn_fmed3f(fmaf(lamB, ia, v.z), m0, M0);
                r.w = __builtin_amdgcn_fmed3f(fmaf(lamB, ia, v.w), m0, M0);
                oB4[tid + k * 256] = r;
            }
        }
    } else {
        // ========== GENERAL PATH: R6 per row from global (unused here) ==========
        for (int rr = 0; rr < 2; ++rr) {
            const int row = rowA + rr;
            if (row >= Btot) break;
            const float4* zr = reinterpret_cast<const float4*>(z + (size_t)row * N);
            float4* orow = reinterpret_cast<float4*>(out + (size_t)row * N);
            const float xir = xi[row];

            float zb[16], ib[16], ma[16], Ma[16];
            float pmin = INFINITY, pmax = -INFINITY, psm = 0.0f, psM = 0.0f;
            #pragma unroll
            for (int k = 0; k < 4; ++k) {
                const int idx = tid + k * 256;
                const float4 zz = zr[idx];
                const float4 gg = g4[idx];
                const float4 mm = m4[idx];
                const float4 MM = M4[idx];
                const float zc[4] = {zz.x, zz.y, zz.z, zz.w};
                const float gc[4] = {gg.x, gg.y, gg.z, gg.w};
                const float mc[4] = {mm.x, mm.y, mm.z, mm.w};
                const float Mc[4] = {MM.x, MM.y, MM.z, MM.w};
                #pragma unroll
                for (int c = 0; c < 4; ++c) {
                    const int j = 4 * k + c;
                    const float tg2 = 2.0f * gc[c];
                    zb[j] = zc[c];
                    ib[j] = 1.0f / tg2;
                    ma[j] = mc[c];
                    Ma[j] = Mc[c];
                    pmin = fminf(pmin, tg2 * (mc[c] - zc[c]));
                    pmax = fmaxf(pmax, tg2 * (Mc[c] - zc[c]));
                    psm += mc[c];
                    psM += Mc[c];
                }
            }
            pmin = wave_min(pmin);
            pmax = wave_max(pmax);
            psm  = wave_sum(psm);
            psM  = wave_sum(psM);
            if (lane == 0) { red[0][wid] = pmin; red[1][wid] = pmax;
                             red[2][wid] = psm;  red[3][wid] = psM; }
            __syncthreads();
            float lo = fminf(fminf(red[0][0], red[0][1]), fminf(red[0][2], red[0][3]));
            float hi = fmaxf(fmaxf(red[1][0], red[1][1]), fmaxf(red[1][2], red[1][3]));
            float glo = ((red[2][0] + red[2][1]) + (red[2][2] + red[2][3])) - xir;
            float ghi = ((red[3][0] + red[3][1]) + (red[3][2] + red[3][3])) - xir;
            int side = 0;

            for (int it = 0; it < TOTAL_STEPS + 1; ++it) {     // 9 proven steps
                const float cand = pick_cand(lo, hi, glo, ghi, it);
                float t0 = 0.f, t1 = 0.f, t2 = 0.f, t3 = 0.f;
                #pragma unroll
                for (int q = 0; q < 4; ++q) {
                    t0 += __builtin_amdgcn_fmed3f(fmaf(cand, ib[4*q+0], zb[4*q+0]), ma[4*q+0], Ma[4*q+0]);
                    t1 += __builtin_amdgcn_fmed3f(fmaf(cand, ib[4*q+1], zb[4*q+1]), ma[4*q+1], Ma[4*q+1]);
                    t2 += __builtin_amdgcn_fmed3f(fmaf(cand, ib[4*q+2], zb[4*q+2]), ma[4*q+2], Ma[4*q+2]);
                    t3 += __builtin_amdgcn_fmed3f(fmaf(cand, ib[4*q+3], zb[4*q+3]), ma[4*q+3], Ma[4*q+3]);
                }
                const float sw = wave_sum((t0 + t1) + (t2 + t3));
                const int p = it & 1;
                if (lane == 0) wsum[p][0][wid] = sw;
                __syncthreads();
                const float s = ((wsum[p][0][0] + wsum[p][0][1]) + (wsum[p][0][2] + wsum[p][0][3])) - xir;
                if (s > 0.0f) { hi = cand; if (side == 1) glo *= 0.5f; ghi = s; side = 1; }
                else          { lo = cand; if (side == -1) ghi *= 0.5f; glo = s; side = -1; }
            }

            const float denom = ghi - glo;
            float lam = (denom > 0.0f) ? (lo * ghi - hi * glo) / denom
                                       : fmaf(0.5f, hi - lo, lo);
            lam = fminf(fmaxf(lam, lo), hi);

            #pragma unroll
            for (int k = 0; k < 4; ++k) {
                float4 r;
                float xs[4];
                #pragma unroll
                for (int c = 0; c < 4; ++c) {
                    const int j = 4 * k + c;
                    xs[c] = __builtin_amdgcn_fmed3f(fmaf(lam, ib[j], zb[j]), ma[j], Ma[j]);
                }
                r.x = xs[0]; r.y = xs[1]; r.z = xs[2]; r.w = xs[3];
                orow[tid + k * 256] = r;
            }
            __syncthreads();   // protect red/wsum reuse across rows
        }
    }
}

extern "C" void kernel_launch(void* const* d_in, const int* in_sizes, int n_in,
                              void* d_out, int out_size, void* d_ws, size_t ws_size,
                              hipStream_t stream) {
    const float* z     = (const float*)d_in[0];
    const float* gamma = (const float*)d_in[1];
    const float* m     = (const float*)d_in[2];
    const float* M     = (const float*)d_in[3];
    const float* xi    = (const float*)d_in[4];
    float* out = (float*)d_out;

    const int B = in_sizes[4];       // rows (xi has one entry per row)
    const int nblocks = (B + 1) / 2;
    // Single dispatch; kernel specialized to N == 4096 (2 rows/block).
    qp_proj2_n4096<<<dim3(nblocks), dim3(256), 0, stream>>>(z, gamma, m, M, xi, out, B);
}